// Round 1
// baseline (642.518 us; speedup 1.0000x reference)
//
#include <hip/hip_runtime.h>

// Problem constants (from reference):
//   B=32, T=2048, D=1536, AUDIO_DIM=1280, V=256, NT=2, NF=2, TR=0.2, FR=0.15
#define AUDIO_DIM_ 1280
#define B_ 32
#define T_ 2048
#define D_ 1536
#define V_ (D_ - AUDIO_DIM_)   // 256

// ---------------------------------------------------------------------------
// Kernel 1: compute per-batch mask interval bounds into ws (B*8 ints).
// Layout per batch b: [t0_0, te_0, t0_1, te_1, f0_0, fe_0, f0_1, fe_1]
// Replicates reference float32 arithmetic exactly:
//   max_t = floor(len * 0.2f); t = floor(u_t * (max_t+1))
//   rem = len - t; t0 = rem<=0 ? 0 : floor(u_t0 * (rem+1))
//   max_f = 192;   f = floor(u_f * 193.0f)
//   f0max = clip(1280 - f, 0); f0 = floor(u_f0 * (f0max+1))
// ---------------------------------------------------------------------------
__global__ void precompute_bounds(const int* __restrict__ lengths,
                                  const float* __restrict__ u_t,
                                  const float* __restrict__ u_t0,
                                  const float* __restrict__ u_f,
                                  const float* __restrict__ u_f0,
                                  int* __restrict__ bounds) {
    int b = threadIdx.x;
    if (b >= B_) return;
    int len = lengths[b];
    float max_t = floorf((float)len * 0.2f);
    int o[8];
    #pragma unroll
    for (int j = 0; j < 2; ++j) {
        int t   = (int)floorf(u_t[j * B_ + b] * (max_t + 1.0f));
        int rem = len - t;
        int t0  = (rem <= 0) ? 0 : (int)floorf(u_t0[j * B_ + b] * ((float)rem + 1.0f));
        o[2 * j]     = t0;
        o[2 * j + 1] = t0 + t;
    }
    #pragma unroll
    for (int j = 0; j < 2; ++j) {
        int f     = (int)floorf(u_f[j * B_ + b] * 193.0f);  // max_f = 192
        int f0max = AUDIO_DIM_ - f;
        if (f0max < 0) f0max = 0;
        int f0    = (int)floorf(u_f0[j * B_ + b] * ((float)f0max + 1.0f));
        o[4 + 2 * j] = f0;
        o[5 + 2 * j] = f0 + f;
    }
    int4* dst = (int4*)(bounds + b * 8);
    dst[0] = make_int4(o[0], o[1], o[2], o[3]);
    dst[1] = make_int4(o[4], o[5], o[6], o[7]);
}

// ---------------------------------------------------------------------------
// Kernel 2: streaming masked copy, float4-vectorized, grid-stride.
// out[b,t,0:256]     = X[b,t,0:256]
// out[b,t,256:1536]  = tmask(b,t) ? 0 : X * !fmask(b, ch)
// ---------------------------------------------------------------------------
__device__ __forceinline__ bool in_iv(int v, int lo, int hi) {
    return (v >= lo) && (v < hi);
}

__global__ __launch_bounds__(256) void specaug_kernel(const float4* __restrict__ X,
                                                      float4* __restrict__ out,
                                                      const int4* __restrict__ bounds) {
    constexpr int ND4  = D_ / 4;        // 384 float4 per row
    constexpr int NV4  = V_ / 4;        // 64 float4 video prefix
    constexpr int NTD4 = T_ * ND4;      // per-batch float4 count
    constexpr int N4   = B_ * NTD4;     // 25,165,824 total

    int stride = gridDim.x * blockDim.x;
    for (int idx = blockIdx.x * blockDim.x + threadIdx.x; idx < N4; idx += stride) {
        int b  = idx / NTD4;
        int r  = idx - b * NTD4;
        int t  = r / ND4;
        int d4 = r - t * ND4;

        float4 x = X[idx];

        if (d4 >= NV4) {
            int4 tb = bounds[2 * b];       // t0_0, te_0, t0_1, te_1
            bool tm = in_iv(t, tb.x, tb.y) || in_iv(t, tb.z, tb.w);
            if (tm) {
                x = make_float4(0.f, 0.f, 0.f, 0.f);
            } else {
                int4 fb = bounds[2 * b + 1];  // f0_0, fe_0, f0_1, fe_1
                int ff = (d4 - NV4) * 4;      // channel index of component .x
                if (in_iv(ff + 0, fb.x, fb.y) || in_iv(ff + 0, fb.z, fb.w)) x.x = 0.f;
                if (in_iv(ff + 1, fb.x, fb.y) || in_iv(ff + 1, fb.z, fb.w)) x.y = 0.f;
                if (in_iv(ff + 2, fb.x, fb.y) || in_iv(ff + 2, fb.z, fb.w)) x.z = 0.f;
                if (in_iv(ff + 3, fb.x, fb.y) || in_iv(ff + 3, fb.z, fb.w)) x.w = 0.f;
            }
        }
        out[idx] = x;
    }
}

extern "C" void kernel_launch(void* const* d_in, const int* in_sizes, int n_in,
                              void* d_out, int out_size, void* d_ws, size_t ws_size,
                              hipStream_t stream) {
    const float* X       = (const float*)d_in[0];
    const int*   lengths = (const int*)  d_in[1];
    const float* u_t     = (const float*)d_in[2];
    const float* u_t0    = (const float*)d_in[3];
    const float* u_f     = (const float*)d_in[4];
    const float* u_f0    = (const float*)d_in[5];
    float*       out     = (float*)d_out;
    int*         bounds  = (int*)d_ws;   // B*8 ints = 1 KiB

    precompute_bounds<<<1, 64, 0, stream>>>(lengths, u_t, u_t0, u_f, u_f0, bounds);

    // 25,165,824 float4 / (12288 blocks * 256 thr) = 8 iterations/thread
    specaug_kernel<<<12288, 256, 0, stream>>>((const float4*)X, (float4*)out,
                                              (const int4*)bounds);
}